// Round 7
// baseline (4904.702 us; speedup 1.0000x reference)
//
#include <hip/hip_runtime.h>
#include <math.h>

#define H 1024
#define BB 64
#define TT 256
#define G3 3072
#define SCAN_BLOCKS 32          // 4 groups x 8 blocks (512-thread blocks)
#define GROUPS 4
#define BPG 8                   // blocks per group (barrier participants)

typedef __attribute__((ext_vector_type(8))) short bf16x8;
typedef __attribute__((ext_vector_type(4))) float f32x4;

__device__ __forceinline__ unsigned short f2bf(float f) {
    union { float f; unsigned int i; } v; v.f = f;
    unsigned int x = v.i;
    unsigned int r = (x + 0x7fffu + ((x >> 16) & 1u)) >> 16;   // RNE
    return (unsigned short)r;
}
__device__ __forceinline__ float bf2f(unsigned short u) {
    union { unsigned int i; float f; } v; v.i = ((unsigned int)u) << 16; return v.f;
}
__device__ __forceinline__ unsigned long long ald8(const unsigned short* p) {
    return __hip_atomic_load((const unsigned long long*)p,
                             __ATOMIC_RELAXED, __HIP_MEMORY_SCOPE_AGENT);
}

// f32 -> bf16 bulk convert (for W_ih), 4 elems/thread
__global__ void cvt_f32_bf16(const float* __restrict__ src,
                             unsigned short* __restrict__ dst) {
    int i = (blockIdx.x * 256 + threadIdx.x) * 4;
    float4 v = *(const float4*)(src + i);
    ushort4 o;
    o.x = f2bf(v.x); o.y = f2bf(v.y); o.z = f2bf(v.z); o.w = f2bf(v.w);
    *(ushort4*)(dst + i) = o;
}

// W_hh -> bf16 in MFMA-fragment order:
// frag idx = ((tau*3 + gate)*32 + kk)*64 + lane, each frag = 8 shorts (16B).
// frag(tau,gate,kk,l) = W[gate*H + tau*16 + (l&15)][(l>>4)*8 + kk*32 .. +8]
__global__ void cvt_whh_perm(const float* __restrict__ src,
                             unsigned short* __restrict__ dst) {
    int idx = blockIdx.x * 256 + threadIdx.x;      // 0 .. 393215
    int tau = idx / 6144;
    int rem = idx % 6144;
    int gate = rem / 2048;
    int r2  = rem % 2048;
    int kk  = r2 >> 6;
    int l   = r2 & 63;
    int srow = gate * H + tau * 16 + (l & 15);
    int scol = (l >> 4) * 8 + kk * 32;
    const float* s = src + (size_t)srow * H + scol;
    float4 u = *(const float4*)s;
    float4 v = *(const float4*)(s + 4);
    unsigned short* d = dst + (size_t)idx * 8;
    d[0] = f2bf(u.x); d[1] = f2bf(u.y); d[2] = f2bf(u.z); d[3] = f2bf(u.w);
    d[4] = f2bf(v.x); d[5] = f2bf(v.y); d[6] = f2bf(v.z); d[7] = f2bf(v.w);
}

// init: hf = h0 (f32), hb = bf16(h0), zero the 4 per-group barrier counters
__global__ void init_all(const float* __restrict__ h0,
                         float* __restrict__ hf, unsigned short* __restrict__ hb,
                         unsigned int* __restrict__ cnt) {
    int i = blockIdx.x * 256 + threadIdx.x;
    if (i < GROUPS) cnt[i * 64] = 0u;  // 256B-spaced counters
    float v = h0[i];
    hf[i] = v;
    hb[i] = f2bf(v);
}

// load 8 consecutive f32, relu, convert to bf16x8
__device__ __forceinline__ bf16x8 load8_relu_bf(const float* p) {
    float4 u = *(const float4*)p;
    float4 v = *(const float4*)(p + 4);
    bf16x8 r;
    r[0] = (short)f2bf(fmaxf(u.x, 0.f));
    r[1] = (short)f2bf(fmaxf(u.y, 0.f));
    r[2] = (short)f2bf(fmaxf(u.z, 0.f));
    r[3] = (short)f2bf(fmaxf(u.w, 0.f));
    r[4] = (short)f2bf(fmaxf(v.x, 0.f));
    r[5] = (short)f2bf(fmaxf(v.y, 0.f));
    r[6] = (short)f2bf(fmaxf(v.z, 0.f));
    r[7] = (short)f2bf(fmaxf(v.w, 0.f));
    return r;
}

// ---- xp_chunk = relu(emb[tokens]) @ W_ih^T + b_ih -> bf16 [Tl*64, 3072] ----
__global__ __launch_bounds__(256) void gemm_xp(
    const float* __restrict__ emb,
    const int* __restrict__ tokens,
    const unsigned short* __restrict__ Wb,
    const float* __restrict__ b_ih,
    unsigned short* __restrict__ xp,
    int row0)
{
    const int tileN = blockIdx.x * 128;
    const int tileM = blockIdx.y * 128;
    const int wave  = threadIdx.x >> 6;
    const int lane  = threadIdx.x & 63;
    const int row   = lane & 15;
    const int quad  = lane >> 4;
    const int mb = tileM + (wave >> 1) * 64;
    const int nb = tileN + (wave & 1) * 64;

    const float* arow[4];
#pragma unroll
    for (int i = 0; i < 4; i++) {
        int tok = tokens[row0 + mb + row + i * 16];
        arow[i] = emb + (size_t)tok * H + quad * 8;
    }
    const unsigned short* bptr = Wb + (size_t)(nb + row) * H + quad * 8;

    f32x4 acc[4][4] = {};
    for (int k = 0; k < H; k += 32) {
        bf16x8 a[4], b[4];
#pragma unroll
        for (int i = 0; i < 4; i++) a[i] = load8_relu_bf(arow[i] + k);
#pragma unroll
        for (int j = 0; j < 4; j++) b[j] = *(const bf16x8*)(bptr + (size_t)j * 16 * H + k);
#pragma unroll
        for (int i = 0; i < 4; i++)
#pragma unroll
            for (int j = 0; j < 4; j++)
                acc[i][j] = __builtin_amdgcn_mfma_f32_16x16x32_bf16(a[i], b[j], acc[i][j], 0, 0, 0);
    }

#pragma unroll
    for (int i = 0; i < 4; i++) {
        int m = mb + i * 16 + quad * 4;
#pragma unroll
        for (int j = 0; j < 4; j++) {
            int n = nb + j * 16 + row;
            float bias = b_ih[n];
#pragma unroll
            for (int rg = 0; rg < 4; rg++) {
                xp[(size_t)(m + rg) * G3 + n] = f2bf(acc[i][j][rg] + bias);
            }
        }
    }
}

// ---- persistent GRU scan (R6 LDS h-dedup, 512-thread blocks) ----
// R6 confirmed the sc1 h-read volume model (4x dedup -> step 11.4->6.5us).
// This round halves the remaining 16x intra-group multicast: 32 blocks of
// 8 waves each (vs 64 x 4), so only 8 readers per group slab -> 1MB/step
// coherent reads, 8 barrier arrivals per group, and 2 waves/SIMD so one
// wave's staging stall overlaps another's MFMA. All else identical to R6
// (fragment-permuted W from L2, fence-free group barrier, 32KB LDS slab).
__global__ __launch_bounds__(512, 2) void gru_scan(
    unsigned short* __restrict__ hb0,          // bf16 h ping [64*1024]
    unsigned short* __restrict__ hb1,          // bf16 h pong
    float* __restrict__ hf,                    // f32 h (chunk handoff)
    const unsigned short* __restrict__ Wp,     // permuted W_hh bf16
    const float* __restrict__ b_hh,            // [3072] f32
    const unsigned short* __restrict__ xp,     // chunk base, [Tl*64, 3072] bf16
    float* __restrict__ out,                   // [B,T,H] f32
    unsigned int* __restrict__ cnt,            // 4 barrier counters, 256B apart
    int t0, int Tl)
{
    const int g    = blockIdx.x >> 3;          // group = batch-row slice
    const int kb   = blockIdx.x & 7;           // block-in-group = col slice
    const int wave = threadIdx.x >> 6;         // 0..7
    const int lane = threadIdx.x & 63;
    const int row  = lane & 15;
    const int quad = lane >> 4;
    const int r0   = g * 16;                   // group's batch rows
    const int c0   = kb * 128 + wave * 16;     // wave's h-cols
    const int cj   = c0 + row;
    unsigned int* cg = cnt + g * 64;           // group counter (256B spacing)

    // h slab in fragment order: frag(kk,l) at (kk*64+l)*8 shorts
    __shared__ unsigned short Hlds[16384];     // 32 KiB

    const float bhr = b_hh[cj];
    const float bhz = b_hh[H + cj];
    const float bhn = b_hh[2 * H + cj];

    // wave's W fragments: tile tau = c0/16; 3 gates at +0 / +16384 / +32768 shorts
    const int tauw = (c0 >> 4);
    const unsigned short* wl = Wp + (size_t)tauw * 49152 + (size_t)lane * 8;

    float hprev[4];
#pragma unroll
    for (int i = 0; i < 4; i++) hprev[i] = hf[(r0 + quad * 4 + i) * H + cj];

    for (int s = 0; s < Tl; s++) {
        const int t = t0 + s;
        const unsigned short* hin  = (t & 1) ? hb1 : hb0;
        unsigned short*       hout = (t & 1) ? hb0 : hb1;

        // ---- cooperative h staging: wave w loads kk in [4w, 4w+4) ----
        // (4KB sc1 per wave; fragment layout the k-loop consumes)
        const unsigned short* hsrc = hin + (size_t)(r0 + row) * H + quad * 8;
        {
            unsigned long long d0[4], d1[4];
#pragma unroll
            for (int u = 0; u < 4; u++) {
                int kk = wave * 4 + u;
                d0[u] = ald8(hsrc + kk * 32);
                d1[u] = ald8(hsrc + kk * 32 + 4);
            }
#pragma unroll
            for (int u = 0; u < 4; u++) {
                int kk = wave * 4 + u;
                union { unsigned long long u64[2]; bf16x8 v; } f;
                f.u64[0] = d0[u]; f.u64[1] = d1[u];
                *(bf16x8*)(Hlds + ((size_t)kk * 64 + lane) * 8) = f.v;
            }
        }

        // xp loads (epilogue-only; independent of h; issue before the sync)
        float xr[4], xz[4], xn[4];
#pragma unroll
        for (int i = 0; i < 4; i++) {
            int b = r0 + quad * 4 + i;
            const unsigned short* xpb = xp + ((size_t)s * BB + b) * G3;
            xr[i] = bf2f(xpb[cj]);
            xz[i] = bf2f(xpb[H + cj]);
            xn[i] = bf2f(xpb[2 * H + cj]);
        }

        __syncthreads();                       // h slab visible to all waves

        f32x4 acc0 = {}, acc1 = {}, acc2 = {};
#pragma unroll
        for (int kk = 0; kk < 32; kk++) {
            bf16x8 a = *(const bf16x8*)(Hlds + ((size_t)kk * 64 + lane) * 8);
            bf16x8 f0 = *(const bf16x8*)(wl + kk * 512);            // gate r
            bf16x8 f1 = *(const bf16x8*)(wl + 16384 + kk * 512);    // gate z
            bf16x8 f2 = *(const bf16x8*)(wl + 32768 + kk * 512);    // gate n
            acc0 = __builtin_amdgcn_mfma_f32_16x16x32_bf16(a, f0, acc0, 0, 0, 0);
            acc1 = __builtin_amdgcn_mfma_f32_16x16x32_bf16(a, f1, acc1, 0, 0, 0);
            acc2 = __builtin_amdgcn_mfma_f32_16x16x32_bf16(a, f2, acc2, 0, 0, 0);
        }

        float hnew[4];
#pragma unroll
        for (int i = 0; i < 4; i++) {
            int b = r0 + quad * 4 + i;
            float hr = acc0[i] + bhr;
            float hz = acc1[i] + bhz;
            float hn = acc2[i] + bhn;
            float r = 1.f / (1.f + __expf(-(xr[i] + hr)));
            float z = 1.f / (1.f + __expf(-(xz[i] + hz)));
            float targ = xn[i] + r * hn;
            targ = fminf(fmaxf(targ, -30.f), 30.f);
            float e2 = __expf(2.f * targ);
            float n = 1.f - 2.f / (e2 + 1.f);           // tanh, fast form
            float hv = (1.f - z) * n + z * hprev[i];
            hv = fminf(fmaxf(hv, -4.f), 4.f);   // invisible when correct
            hprev[i] = hv;
            hnew[i] = hv;

            // h store: pair adjacent cols (lanes l, l^1) into one 4B
            // write-through agent-scope atomic store.
            unsigned int mybf = (unsigned int)f2bf(hv);
            unsigned int pbf  = (unsigned int)__shfl_xor((int)mybf, 1);
            if (!(row & 1)) {
                unsigned int word = (mybf & 0xffffu) | (pbf << 16);
                __hip_atomic_store((unsigned int*)(hout + (size_t)b * H + (cj & ~1)),
                                   word, __ATOMIC_RELAXED, __HIP_MEMORY_SCOPE_AGENT);
            }
        }

        // ---- group barrier: arrive early, overlap out-stores with wait ----
        // (the __syncthreads here also fences Hlds reuse across steps)
        asm volatile("s_waitcnt vmcnt(0)" ::: "memory");   // h stores acked at L3
        __syncthreads();                                   // all 8 waves drained
        if (threadIdx.x == 0)
            __hip_atomic_fetch_add(cg, 1u, __ATOMIC_RELAXED, __HIP_MEMORY_SCOPE_AGENT);

        // out stores (normal, write-back) overlap with the barrier wait
#pragma unroll
        for (int i = 0; i < 4; i++) {
            int b = r0 + quad * 4 + i;
            out[((size_t)b * TT + t) * H + cj] = hnew[i];
        }

        // per-wave poll: wave proceeds as soon as its group is done
        if (lane == 0) {
            const unsigned int target = (unsigned int)(t + 1) * BPG;
            while (__hip_atomic_load(cg, __ATOMIC_RELAXED, __HIP_MEMORY_SCOPE_AGENT) < target) {
                __builtin_amdgcn_s_sleep(1);
            }
        }
        asm volatile("" ::: "memory");   // no hoisting of next-step h loads above poll
    }

#pragma unroll
    for (int i = 0; i < 4; i++) hf[(r0 + quad * 4 + i) * H + cj] = hprev[i];
}

extern "C" void kernel_launch(void* const* d_in, const int* in_sizes, int n_in,
                              void* d_out, int out_size, void* d_ws, size_t ws_size,
                              hipStream_t stream) {
    const int*   tokens = (const int*)d_in[0];
    const float* h0     = (const float*)d_in[1];
    const float* emb    = (const float*)d_in[2];
    const float* W_ih   = (const float*)d_in[3];
    const float* W_hh   = (const float*)d_in[4];
    const float* b_ih   = (const float*)d_in[5];
    const float* b_hh   = (const float*)d_in[6];
    float*       out    = (float*)d_out;

    // ws: [0,1MiB) h state + barriers | [1MiB,+6MiB) W_ih bf16 | +6MiB W_hh perm bf16 | xp chunk
    char* ws = (char*)d_ws;
    float* hf0 = (float*)ws;                                // 256 KiB (f32 h)
    unsigned short* hb0 = (unsigned short*)(ws + 524288);   // 128 KiB
    unsigned short* hb1 = hb0 + BB * H;                     // 128 KiB
    unsigned int* cnt = (unsigned int*)(ws + 786432);       // 4 counters, 256B apart
    unsigned short* Wib = (unsigned short*)(ws + 1048576);          // 6 MiB
    unsigned short* Wpb = (unsigned short*)(ws + 1048576 + 6291456);// 6 MiB (permuted)
    unsigned short* xp  = (unsigned short*)(ws + 13631488);

    const size_t slab = (size_t)BB * G3 * 2;                // 393,216 B per t
    long avail = (long)ws_size - 13631488L;
    if (avail < 0) avail = 0;
    long tc = (avail / (long)slab) & ~1L;                   // even
    if (tc < 2) tc = 2;
    if (tc > TT) tc = TT;
    const int Tc = (int)tc;

    hipLaunchKernelGGL(cvt_f32_bf16, dim3(G3 * H / 1024), dim3(256), 0, stream, W_ih, Wib);
    hipLaunchKernelGGL(cvt_whh_perm, dim3(1536), dim3(256), 0, stream, W_hh, Wpb);
    hipLaunchKernelGGL(init_all, dim3((BB * H) / 256), dim3(256), 0, stream, h0, hf0, hb0, cnt);

    for (int c0 = 0; c0 < TT; c0 += Tc) {
        const int Tl = (TT - c0 < Tc) ? (TT - c0) : Tc;     // even
        hipLaunchKernelGGL(gemm_xp, dim3(G3 / 128, Tl * BB / 128), dim3(256), 0, stream,
                           emb, tokens, Wib, b_ih, xp, c0 * BB);
        hipLaunchKernelGGL(gru_scan, dim3(SCAN_BLOCKS), dim3(512), 0, stream,
                           hb0, hb1, hf0, Wpb, b_hh, xp, out, cnt, c0, Tl);
    }
}

// Round 8
// 2224.799 us; speedup vs baseline: 2.2046x; 2.2046x over previous
//
#include <hip/hip_runtime.h>
#include <math.h>

#define H 1024
#define BB 64
#define TT 256
#define G3 3072
#define SCAN_BLOCKS 64          // 4 groups x 16 blocks (proven R6 structure)
#define GROUPS 4
#define BPG 16                  // blocks per group (barrier participants)

typedef __attribute__((ext_vector_type(8))) short bf16x8;
typedef __attribute__((ext_vector_type(4))) float f32x4;

__device__ __forceinline__ unsigned short f2bf(float f) {
    union { float f; unsigned int i; } v; v.f = f;
    unsigned int x = v.i;
    unsigned int r = (x + 0x7fffu + ((x >> 16) & 1u)) >> 16;   // RNE
    return (unsigned short)r;
}
__device__ __forceinline__ float bf2f(unsigned short u) {
    union { unsigned int i; float f; } v; v.i = ((unsigned int)u) << 16; return v.f;
}
__device__ __forceinline__ unsigned long long ald8(const unsigned short* p) {
    return __hip_atomic_load((const unsigned long long*)p,
                             __ATOMIC_RELAXED, __HIP_MEMORY_SCOPE_AGENT);
}

// f32 -> bf16 bulk convert (for W_ih), 4 elems/thread
__global__ void cvt_f32_bf16(const float* __restrict__ src,
                             unsigned short* __restrict__ dst) {
    int i = (blockIdx.x * 256 + threadIdx.x) * 4;
    float4 v = *(const float4*)(src + i);
    ushort4 o;
    o.x = f2bf(v.x); o.y = f2bf(v.y); o.z = f2bf(v.z); o.w = f2bf(v.w);
    *(ushort4*)(dst + i) = o;
}

// W_hh -> bf16 in MFMA-fragment order:
// frag idx = ((tau*3 + gate)*32 + kk)*64 + lane, each frag = 8 shorts (16B).
// frag(tau,gate,kk,l) = W[gate*H + tau*16 + (l&15)][(l>>4)*8 + kk*32 .. +8]
__global__ void cvt_whh_perm(const float* __restrict__ src,
                             unsigned short* __restrict__ dst) {
    int idx = blockIdx.x * 256 + threadIdx.x;      // 0 .. 393215
    int tau = idx / 6144;
    int rem = idx % 6144;
    int gate = rem / 2048;
    int r2  = rem % 2048;
    int kk  = r2 >> 6;
    int l   = r2 & 63;
    int srow = gate * H + tau * 16 + (l & 15);
    int scol = (l >> 4) * 8 + kk * 32;
    const float* s = src + (size_t)srow * H + scol;
    float4 u = *(const float4*)s;
    float4 v = *(const float4*)(s + 4);
    unsigned short* d = dst + (size_t)idx * 8;
    d[0] = f2bf(u.x); d[1] = f2bf(u.y); d[2] = f2bf(u.z); d[3] = f2bf(u.w);
    d[4] = f2bf(v.x); d[5] = f2bf(v.y); d[6] = f2bf(v.z); d[7] = f2bf(v.w);
}

// init: hf = h0 (f32), hb = bf16(h0), zero the 4 per-group barrier counters
__global__ void init_all(const float* __restrict__ h0,
                         float* __restrict__ hf, unsigned short* __restrict__ hb,
                         unsigned int* __restrict__ cnt) {
    int i = blockIdx.x * 256 + threadIdx.x;
    if (i < GROUPS) cnt[i * 64] = 0u;  // 256B-spaced counters
    float v = h0[i];
    hf[i] = v;
    hb[i] = f2bf(v);
}

// ---- x_bf[m,k] = bf16(relu(emb[tokens[row0+m]][k])) for one chunk ----
// One-pass gather+relu+convert: 8 elems/thread, float4 loads, ushort8 store.
// Removes the 24x re-gather + per-k f32->bf16 VALU from gemm_xp's inner loop.
__global__ __launch_bounds__(256) void cvt_x(
    const float* __restrict__ emb,
    const int* __restrict__ tokens,
    unsigned short* __restrict__ xb,
    int row0)
{
    int idx = blockIdx.x * 256 + threadIdx.x;   // one per 8 elems
    int m   = idx >> 7;                         // chunk-local row (H/8=128 per row)
    int k8  = (idx & 127) * 8;
    int tok = tokens[row0 + m];
    const float* s = emb + (size_t)tok * H + k8;
    float4 u = *(const float4*)s;
    float4 v = *(const float4*)(s + 4);
    ushort4 o0, o1;
    o0.x = f2bf(fmaxf(u.x, 0.f)); o0.y = f2bf(fmaxf(u.y, 0.f));
    o0.z = f2bf(fmaxf(u.z, 0.f)); o0.w = f2bf(fmaxf(u.w, 0.f));
    o1.x = f2bf(fmaxf(v.x, 0.f)); o1.y = f2bf(fmaxf(v.y, 0.f));
    o1.z = f2bf(fmaxf(v.z, 0.f)); o1.w = f2bf(fmaxf(v.w, 0.f));
    unsigned short* d = xb + (size_t)m * H + k8;
    *(ushort4*)d = o0;
    *(ushort4*)(d + 4) = o1;
}

// ---- xp_chunk = x_bf @ W_ih^T + b_ih -> bf16 [Tl*64, 3072] ----
// A is now pre-converted bf16 (cvt_x): pure bf16x8 loads in the k-loop,
// no gather, no per-k relu/convert VALU.
__global__ __launch_bounds__(256) void gemm_xp(
    const unsigned short* __restrict__ xb,
    const unsigned short* __restrict__ Wb,
    const float* __restrict__ b_ih,
    unsigned short* __restrict__ xp)
{
    const int tileN = blockIdx.x * 128;
    const int tileM = blockIdx.y * 128;
    const int wave  = threadIdx.x >> 6;
    const int lane  = threadIdx.x & 63;
    const int row   = lane & 15;
    const int quad  = lane >> 4;
    const int mb = tileM + (wave >> 1) * 64;
    const int nb = tileN + (wave & 1) * 64;

    const unsigned short* arow[4];
#pragma unroll
    for (int i = 0; i < 4; i++)
        arow[i] = xb + (size_t)(mb + row + i * 16) * H + quad * 8;
    const unsigned short* bptr = Wb + (size_t)(nb + row) * H + quad * 8;

    f32x4 acc[4][4] = {};
    for (int k = 0; k < H; k += 32) {
        bf16x8 a[4], b[4];
#pragma unroll
        for (int i = 0; i < 4; i++) a[i] = *(const bf16x8*)(arow[i] + k);
#pragma unroll
        for (int j = 0; j < 4; j++) b[j] = *(const bf16x8*)(bptr + (size_t)j * 16 * H + k);
#pragma unroll
        for (int i = 0; i < 4; i++)
#pragma unroll
            for (int j = 0; j < 4; j++)
                acc[i][j] = __builtin_amdgcn_mfma_f32_16x16x32_bf16(a[i], b[j], acc[i][j], 0, 0, 0);
    }

#pragma unroll
    for (int i = 0; i < 4; i++) {
        int m = mb + i * 16 + quad * 4;
#pragma unroll
        for (int j = 0; j < 4; j++) {
            int n = nb + j * 16 + row;
            float bias = b_ih[n];
#pragma unroll
            for (int rg = 0; rg < 4; rg++) {
                xp[(size_t)(m + rg) * G3 + n] = f2bf(acc[i][j][rg] + bias);
            }
        }
    }
}

// ---- persistent GRU scan (R6 verbatim: LDS h-dedup, 4x64-block groups) ----
// R6 confirmed the sc1 h-read volume model (4x dedup -> step 11.4->6.5us).
// R7's 512-thread variant regressed via launch_bounds VGPR cap (128) ->
// scratch spills; reverted to this proven structure.
__global__ __launch_bounds__(256, 1) void gru_scan(
    unsigned short* __restrict__ hb0,          // bf16 h ping [64*1024]
    unsigned short* __restrict__ hb1,          // bf16 h pong
    float* __restrict__ hf,                    // f32 h (chunk handoff)
    const unsigned short* __restrict__ Wp,     // permuted W_hh bf16
    const float* __restrict__ b_hh,            // [3072] f32
    const unsigned short* __restrict__ xp,     // chunk base, [Tl*64, 3072] bf16
    float* __restrict__ out,                   // [B,T,H] f32
    unsigned int* __restrict__ cnt,            // 4 barrier counters, 256B apart
    int t0, int Tl)
{
    const int g    = blockIdx.x >> 4;          // group = batch-row slice
    const int kb   = blockIdx.x & 15;          // block-in-group = col slice
    const int wave = threadIdx.x >> 6;
    const int lane = threadIdx.x & 63;
    const int row  = lane & 15;
    const int quad = lane >> 4;
    const int r0   = g * 16;                   // group's batch rows
    const int c0   = kb * 64 + wave * 16;      // wave's h-cols
    const int cj   = c0 + row;
    unsigned int* cg = cnt + g * 64;           // group counter (256B spacing)

    // h slab in fragment order: frag(kk,l) at (kk*64+l)*8 shorts
    __shared__ unsigned short Hlds[16384];     // 32 KiB

    const float bhr = b_hh[cj];
    const float bhz = b_hh[H + cj];
    const float bhn = b_hh[2 * H + cj];

    // wave's W fragments: tile tau = c0/16; 3 gates at +0 / +16384 / +32768 shorts
    const int tauw = (c0 >> 4);
    const unsigned short* wl = Wp + (size_t)tauw * 49152 + (size_t)lane * 8;

    float hprev[4];
#pragma unroll
    for (int i = 0; i < 4; i++) hprev[i] = hf[(r0 + quad * 4 + i) * H + cj];

    for (int s = 0; s < Tl; s++) {
        const int t = t0 + s;
        const unsigned short* hin  = (t & 1) ? hb1 : hb0;
        unsigned short*       hout = (t & 1) ? hb0 : hb1;

        // ---- cooperative h staging: wave w loads kk in [8w, 8w+8) ----
        const unsigned short* hsrc = hin + (size_t)(r0 + row) * H + quad * 8;
        {
            unsigned long long d0[8], d1[8];
#pragma unroll
            for (int u = 0; u < 8; u++) {
                int kk = wave * 8 + u;
                d0[u] = ald8(hsrc + kk * 32);
                d1[u] = ald8(hsrc + kk * 32 + 4);
            }
#pragma unroll
            for (int u = 0; u < 8; u++) {
                int kk = wave * 8 + u;
                union { unsigned long long u64[2]; bf16x8 v; } f;
                f.u64[0] = d0[u]; f.u64[1] = d1[u];
                *(bf16x8*)(Hlds + ((size_t)kk * 64 + lane) * 8) = f.v;
            }
        }

        // xp loads (epilogue-only; independent of h; issue before the sync)
        float xr[4], xz[4], xn[4];
#pragma unroll
        for (int i = 0; i < 4; i++) {
            int b = r0 + quad * 4 + i;
            const unsigned short* xpb = xp + ((size_t)s * BB + b) * G3;
            xr[i] = bf2f(xpb[cj]);
            xz[i] = bf2f(xpb[H + cj]);
            xn[i] = bf2f(xpb[2 * H + cj]);
        }

        __syncthreads();                       // h slab visible to all waves

        f32x4 acc0 = {}, acc1 = {}, acc2 = {};
#pragma unroll
        for (int kk = 0; kk < 32; kk++) {
            bf16x8 a = *(const bf16x8*)(Hlds + ((size_t)kk * 64 + lane) * 8);
            bf16x8 f0 = *(const bf16x8*)(wl + kk * 512);            // gate r
            bf16x8 f1 = *(const bf16x8*)(wl + 16384 + kk * 512);    // gate z
            bf16x8 f2 = *(const bf16x8*)(wl + 32768 + kk * 512);    // gate n
            acc0 = __builtin_amdgcn_mfma_f32_16x16x32_bf16(a, f0, acc0, 0, 0, 0);
            acc1 = __builtin_amdgcn_mfma_f32_16x16x32_bf16(a, f1, acc1, 0, 0, 0);
            acc2 = __builtin_amdgcn_mfma_f32_16x16x32_bf16(a, f2, acc2, 0, 0, 0);
        }

        float hnew[4];
#pragma unroll
        for (int i = 0; i < 4; i++) {
            int b = r0 + quad * 4 + i;
            float hr = acc0[i] + bhr;
            float hz = acc1[i] + bhz;
            float hn = acc2[i] + bhn;
            float r = 1.f / (1.f + __expf(-(xr[i] + hr)));
            float z = 1.f / (1.f + __expf(-(xz[i] + hz)));
            float targ = xn[i] + r * hn;
            targ = fminf(fmaxf(targ, -30.f), 30.f);
            float e2 = __expf(2.f * targ);
            float n = 1.f - 2.f / (e2 + 1.f);           // tanh, fast form
            float hv = (1.f - z) * n + z * hprev[i];
            hv = fminf(fmaxf(hv, -4.f), 4.f);   // invisible when correct
            hprev[i] = hv;
            hnew[i] = hv;

            // h store: pair adjacent cols (lanes l, l^1) into one 4B
            // write-through agent-scope atomic store.
            unsigned int mybf = (unsigned int)f2bf(hv);
            unsigned int pbf  = (unsigned int)__shfl_xor((int)mybf, 1);
            if (!(row & 1)) {
                unsigned int word = (mybf & 0xffffu) | (pbf << 16);
                __hip_atomic_store((unsigned int*)(hout + (size_t)b * H + (cj & ~1)),
                                   word, __ATOMIC_RELAXED, __HIP_MEMORY_SCOPE_AGENT);
            }
        }

        // ---- group barrier: arrive early, overlap out-stores with wait ----
        asm volatile("s_waitcnt vmcnt(0)" ::: "memory");   // h stores acked at L3
        __syncthreads();                                   // all 4 waves drained
        if (threadIdx.x == 0)
            __hip_atomic_fetch_add(cg, 1u, __ATOMIC_RELAXED, __HIP_MEMORY_SCOPE_AGENT);

        // out stores (normal, write-back) overlap with the barrier wait
#pragma unroll
        for (int i = 0; i < 4; i++) {
            int b = r0 + quad * 4 + i;
            out[((size_t)b * TT + t) * H + cj] = hnew[i];
        }

        // per-wave poll: wave proceeds as soon as its group is done
        if (lane == 0) {
            const unsigned int target = (unsigned int)(t + 1) * BPG;
            while (__hip_atomic_load(cg, __ATOMIC_RELAXED, __HIP_MEMORY_SCOPE_AGENT) < target) {
                __builtin_amdgcn_s_sleep(1);
            }
        }
        asm volatile("" ::: "memory");   // no hoisting of next-step h loads above poll
    }

#pragma unroll
    for (int i = 0; i < 4; i++) hf[(r0 + quad * 4 + i) * H + cj] = hprev[i];
}

extern "C" void kernel_launch(void* const* d_in, const int* in_sizes, int n_in,
                              void* d_out, int out_size, void* d_ws, size_t ws_size,
                              hipStream_t stream) {
    const int*   tokens = (const int*)d_in[0];
    const float* h0     = (const float*)d_in[1];
    const float* emb    = (const float*)d_in[2];
    const float* W_ih   = (const float*)d_in[3];
    const float* W_hh   = (const float*)d_in[4];
    const float* b_ih   = (const float*)d_in[5];
    const float* b_hh   = (const float*)d_in[6];
    float*       out    = (float*)d_out;

    // ws: [0,1MiB) h state + barriers | [1MiB,+6MiB) W_ih bf16 | +6MiB W_hh perm bf16
    //     | xp chunk (Tc*384KiB) | x_bf chunk (Tc*128KiB)
    char* ws = (char*)d_ws;
    float* hf0 = (float*)ws;                                // 256 KiB (f32 h)
    unsigned short* hb0 = (unsigned short*)(ws + 524288);   // 128 KiB
    unsigned short* hb1 = hb0 + BB * H;                     // 128 KiB
    unsigned int* cnt = (unsigned int*)(ws + 786432);       // 4 counters, 256B apart
    unsigned short* Wib = (unsigned short*)(ws + 1048576);          // 6 MiB
    unsigned short* Wpb = (unsigned short*)(ws + 1048576 + 6291456);// 6 MiB (permuted)

    const long slab_xp = (long)BB * G3 * 2;                 // 393,216 B per t
    const long slab_xb = (long)BB * H * 2;                  // 131,072 B per t
    long avail = (long)ws_size - 13631488L;
    if (avail < 0) avail = 0;
    long tc = (avail / (slab_xp + slab_xb)) & ~1L;          // even
    if (tc < 2) tc = 2;
    if (tc > TT) tc = TT;
    const int Tc = (int)tc;
    unsigned short* xp = (unsigned short*)(ws + 13631488);
    unsigned short* xb = (unsigned short*)(ws + 13631488 + (size_t)Tc * slab_xp);

    hipLaunchKernelGGL(cvt_f32_bf16, dim3(G3 * H / 1024), dim3(256), 0, stream, W_ih, Wib);
    hipLaunchKernelGGL(cvt_whh_perm, dim3(1536), dim3(256), 0, stream, W_hh, Wpb);
    hipLaunchKernelGGL(init_all, dim3((BB * H) / 256), dim3(256), 0, stream, h0, hf0, hb0, cnt);

    for (int c0 = 0; c0 < TT; c0 += Tc) {
        const int Tl = (TT - c0 < Tc) ? (TT - c0) : Tc;     // even
        hipLaunchKernelGGL(cvt_x, dim3(Tl * 32), dim3(256), 0, stream,
                           emb, tokens, xb, c0 * BB);
        hipLaunchKernelGGL(gemm_xp, dim3(G3 / 128, Tl * BB / 128), dim3(256), 0, stream,
                           xb, Wib, b_ih, xp);
        hipLaunchKernelGGL(gru_scan, dim3(SCAN_BLOCKS), dim3(256), 0, stream,
                           hb0, hb1, hf0, Wpb, b_hh, xp, out, cnt, c0, Tl);
    }
}